// Round 1
// baseline (3526.862 us; speedup 1.0000x reference)
//
#include <hip/hip_runtime.h>
#include <hip/hip_bf16.h>

// Problem constants
#define B_    8
#define C_    512
#define N_    8192
#define H_    8
#define D_    64
#define HID_  1024

constexpr float EPS_ATTN = 1e-6f;
constexpr float EPS_BN   = 1e-5f;

// =====================================================================
// Generic channel-major GEMM: OUT[b,o,n] = sum_c Wval(c,o) * IN[b,c,n]
//   WLAYOUT 0: W[c*ldw + o]   (qkv_w, proj_w: stored [C, O])
//   WLAYOUT 1: W[o*ldw + c]   (w1, w2: stored [O, C])
//   EPI 0: raw write
//   EPI 1: +bias, phi (elu+1) for o < phi_limit   (qkv)
//   EPI 2: +bias, +residual                        (proj)
//   IN_TRANS: input transform relu(in*scale[c]+shift[c])  (BN+ReLU fused, w2)
// Tile: 128(O) x 128(N), TC=8, 256 threads, 8x8 per-thread micro-tile.
// =====================================================================
template<int WLAYOUT, int EPI, bool IN_TRANS>
__global__ __launch_bounds__(256)
void gemm_cn(const float* __restrict__ W, int ldw,
             const float* __restrict__ IN, size_t in_bstride,
             float* __restrict__ OUT, size_t out_bstride,
             int C,
             const float* __restrict__ bias,
             const float* __restrict__ resid, size_t res_bstride,
             const float* __restrict__ in_scale,
             const float* __restrict__ in_shift,
             int phi_limit)
{
    constexpr int TO = 128, TN = 128, TC = 8, PAD = 4;
    __shared__ float Ws[TC][TO + PAD];
    __shared__ float Is[TC][TN + PAD];

    const int tid = threadIdx.x;
    const int tx = tid & 15;        // n-dir, 16 cols
    const int ty = tid >> 4;        // o-dir, 16 rows
    const int b = blockIdx.z;
    const int o_base = blockIdx.y * TO;
    const int n_base = blockIdx.x * TN;

    const float* __restrict__ INb = IN + (size_t)b * in_bstride;

    float acc[8][8];
    #pragma unroll
    for (int i = 0; i < 8; i++) {
        #pragma unroll
        for (int j = 0; j < 8; j++) acc[i][j] = 0.f;
    }

    for (int c0 = 0; c0 < C; c0 += TC) {
        // ---- stage W tile: Ws[cc][o_local] ----
        if (WLAYOUT == 0) {
            const int r = tid >> 5, o4 = (tid & 31) * 4;
            float4 w = *(const float4*)(W + (size_t)(c0 + r) * ldw + o_base + o4);
            *(float4*)&Ws[r][o4] = w;
        } else {
            const int o = tid & 127, cg = (tid >> 7) * 4;
            float4 w = *(const float4*)(W + (size_t)(o_base + o) * ldw + c0 + cg);
            Ws[cg + 0][o] = w.x; Ws[cg + 1][o] = w.y;
            Ws[cg + 2][o] = w.z; Ws[cg + 3][o] = w.w;
        }
        // ---- stage IN tile: Is[cc][n_local] (optional BN+ReLU transform) ----
        {
            const int r = tid >> 5, c4 = (tid & 31) * 4;
            float4 v = *(const float4*)(INb + (size_t)(c0 + r) * N_ + n_base + c4);
            if (IN_TRANS) {
                const float sc = in_scale[c0 + r], sf = in_shift[c0 + r];
                v.x = fmaxf(fmaf(v.x, sc, sf), 0.f);
                v.y = fmaxf(fmaf(v.y, sc, sf), 0.f);
                v.z = fmaxf(fmaf(v.z, sc, sf), 0.f);
                v.w = fmaxf(fmaf(v.w, sc, sf), 0.f);
            }
            *(float4*)&Is[r][c4] = v;
        }
        __syncthreads();
        #pragma unroll
        for (int cc = 0; cc < TC; ++cc) {
            float a[8], bv[8];
            *(float4*)&a[0]  = *(const float4*)&Ws[cc][ty * 4];
            *(float4*)&a[4]  = *(const float4*)&Ws[cc][64 + ty * 4];
            *(float4*)&bv[0] = *(const float4*)&Is[cc][tx * 4];
            *(float4*)&bv[4] = *(const float4*)&Is[cc][64 + tx * 4];
            #pragma unroll
            for (int i = 0; i < 8; i++) {
                #pragma unroll
                for (int j = 0; j < 8; j++)
                    acc[i][j] = fmaf(a[i], bv[j], acc[i][j]);
            }
        }
        __syncthreads();
    }

    // ---- epilogue + store ----
    #pragma unroll
    for (int i = 0; i < 8; i++) {
        const int ol = (i < 4) ? (ty * 4 + i) : (64 + ty * 4 + (i - 4));
        const int og = o_base + ol;
        float bi = 0.f;
        if (EPI >= 1) bi = bias[og];
        float* __restrict__ orow = OUT + (size_t)b * out_bstride + (size_t)og * N_ + n_base;
        #pragma unroll
        for (int jg = 0; jg < 2; jg++) {
            const int nl = jg * 64 + tx * 4;
            float vals[4];
            #pragma unroll
            for (int j = 0; j < 4; j++) vals[j] = acc[i][jg * 4 + j] + bi;
            if (EPI == 1) {
                if (og < phi_limit) {  // phi(x) = elu(x)+1 = x>0 ? x+1 : exp(x)
                    #pragma unroll
                    for (int j = 0; j < 4; j++)
                        vals[j] = vals[j] > 0.f ? vals[j] + 1.f : expf(vals[j]);
                }
            }
            if (EPI == 2) {
                const float4 rv = *(const float4*)(resid + (size_t)b * res_bstride
                                                   + (size_t)og * N_ + n_base + nl);
                vals[0] += rv.x; vals[1] += rv.y; vals[2] += rv.z; vals[3] += rv.w;
            }
            float4 r;
            r.x = vals[0]; r.y = vals[1]; r.z = vals[2]; r.w = vals[3];
            *(float4*)(orow + nl) = r;
        }
    }
}

// =====================================================================
// Attention stage 1: S[bh,d,e] = sum_n k_phi[d,n]*v[e,n]; ksum[bh,d]
// grid (8 n-chunks of 1024, 64 bh); fp32 atomics into pre-zeroed ws.
// =====================================================================
__global__ __launch_bounds__(256)
void attn_kv(const float* __restrict__ qkv, float* __restrict__ S, float* __restrict__ ksum)
{
    constexpr int TNK = 16;
    __shared__ float kt[64][21];   // stride 21 (odd) -> conflict-free column reads
    __shared__ float vt[64][21];
    const int tid = threadIdx.x;
    const int bh = blockIdx.y;
    const int b = bh >> 3, h = bh & 7;
    const size_t kbase = ((size_t)b * 1536 + 512  + h * 64) * N_;
    const size_t vbase = ((size_t)b * 1536 + 1024 + h * 64) * N_;
    const int n0 = blockIdx.x * 1024;

    const int e  = tid & 63;      // v-column owned by this lane
    const int dg = tid >> 6;      // wave id -> d-group (wave-uniform => broadcast reads)
    float s[16];
    #pragma unroll
    for (int i = 0; i < 16; i++) s[i] = 0.f;
    float ksl = 0.f;

    const int lr = tid >> 2;            // staging row 0..63
    const int lc = (tid & 3) * 4;       // staging col 0,4,8,12

    for (int it = 0; it < 1024 / TNK; ++it) {
        const int nt = n0 + it * TNK;
        const float4 k4 = *(const float4*)(qkv + kbase + (size_t)lr * N_ + nt + lc);
        const float4 v4 = *(const float4*)(qkv + vbase + (size_t)lr * N_ + nt + lc);
        __syncthreads();
        kt[lr][lc + 0] = k4.x; kt[lr][lc + 1] = k4.y; kt[lr][lc + 2] = k4.z; kt[lr][lc + 3] = k4.w;
        vt[lr][lc + 0] = v4.x; vt[lr][lc + 1] = v4.y; vt[lr][lc + 2] = v4.z; vt[lr][lc + 3] = v4.w;
        __syncthreads();
        if (tid < 64) {   // wave 0 (uniform branch): ksum partials
            float kk = 0.f;
            #pragma unroll
            for (int nn = 0; nn < TNK; nn++) kk += kt[tid][nn];
            ksl += kk;
        }
        #pragma unroll
        for (int nn = 0; nn < TNK; nn++) {
            const float ve = vt[e][nn];
            #pragma unroll
            for (int i = 0; i < 16; i++)
                s[i] = fmaf(kt[dg * 16 + i][nn], ve, s[i]);
        }
    }
    float* Sb = S + (size_t)bh * 64 * 64;
    #pragma unroll
    for (int i = 0; i < 16; i++)
        atomicAdd(&Sb[(dg * 16 + i) * 64 + e], s[i]);
    if (tid < 64) atomicAdd(&ksum[bh * 64 + tid], ksl);
}

// =====================================================================
// Attention stage 2: out[e,n] = (sum_d q[d,n]*S[d,e]) / (sum_d q[d,n]*ks[d] + eps)
// Writes into the v-slot of the qkv buffer (v already consumed by attn_kv).
// S/ks reads are block-uniform -> compiler scalarizes to s_load.
// =====================================================================
__global__ __launch_bounds__(256)
void attn_apply(float* __restrict__ qkv, const float* __restrict__ S, const float* __restrict__ ksum)
{
    const int tid = threadIdx.x;
    const int bh = blockIdx.y;
    const int b = bh >> 3, h = bh & 7;
    const int n = blockIdx.x * 256 + tid;
    const float* __restrict__ qb = qkv + ((size_t)b * 1536 + h * 64) * N_ + n;
    const float* __restrict__ Sb = S + (size_t)bh * 4096;
    const float* __restrict__ ks = ksum + bh * 64;
    float acc[64];
    #pragma unroll
    for (int e = 0; e < 64; e++) acc[e] = 0.f;
    float den = EPS_ATTN;
    for (int d = 0; d < 64; ++d) {
        const float qd = qb[(size_t)d * N_];
        den = fmaf(qd, ks[d], den);
        #pragma unroll
        for (int e = 0; e < 64; e++)
            acc[e] = fmaf(qd, Sb[d * 64 + e], acc[e]);
    }
    const float inv = 1.0f / den;
    float* __restrict__ ob = qkv + ((size_t)b * 1536 + 1024 + h * 64) * N_ + n;
    #pragma unroll
    for (int e = 0; e < 64; e++) ob[(size_t)e * N_] = acc[e] * inv;
}

// =====================================================================
// BatchNorm stats over (b, n) per channel -> scale/shift form.
// Double accumulation (cheap; kernel is HBM-bound anyway).
// =====================================================================
__global__ __launch_bounds__(256)
void bn_stats(const float* __restrict__ X, size_t bstride,
              const float* __restrict__ gamma, const float* __restrict__ beta,
              float* __restrict__ scale, float* __restrict__ shift)
{
    const int ch = blockIdx.x;
    const int tid = threadIdx.x;
    double s = 0.0, s2 = 0.0;
    for (int b = 0; b < B_; ++b) {
        const float4* base = (const float4*)(X + (size_t)b * bstride + (size_t)ch * N_);
        for (int i = tid; i < N_ / 4; i += 256) {
            const float4 v = base[i];
            s  += (double)v.x + (double)v.y + (double)v.z + (double)v.w;
            s2 += (double)v.x * v.x + (double)v.y * v.y + (double)v.z * v.z + (double)v.w * v.w;
        }
    }
    __shared__ double sh[256], sh2[256];
    sh[tid] = s; sh2[tid] = s2;
    __syncthreads();
    for (int off = 128; off > 0; off >>= 1) {
        if (tid < off) { sh[tid] += sh[tid + off]; sh2[tid] += sh2[tid + off]; }
        __syncthreads();
    }
    if (tid == 0) {
        const double n = (double)B_ * (double)N_;
        const double mean = sh[0] / n;
        const double var  = sh2[0] / n - mean * mean;
        const double inv  = 1.0 / sqrt(var + (double)EPS_BN);
        const double g = (double)gamma[ch];
        scale[ch] = (float)(g * inv);
        shift[ch] = (float)((double)beta[ch] - mean * g * inv);
    }
}

// =====================================================================
// Final: out += relu(h2*scale2[c] + shift2[c])   (out already holds x1)
// =====================================================================
__global__ __launch_bounds__(256)
void final_add(float* __restrict__ out, const float* __restrict__ h2,
               const float* __restrict__ scale, const float* __restrict__ shift)
{
    const size_t i = (size_t)blockIdx.x * 256 + threadIdx.x;   // float4 index
    const int c = (int)((i >> 11) & (C_ - 1));                 // N/4 = 2048 float4 per row
    const float sc = scale[c], sf = shift[c];
    const float4 hv = ((const float4*)h2)[i];
    float4 xv = ((float4*)out)[i];
    xv.x += fmaxf(fmaf(hv.x, sc, sf), 0.f);
    xv.y += fmaxf(fmaf(hv.y, sc, sf), 0.f);
    xv.z += fmaxf(fmaf(hv.z, sc, sf), 0.f);
    xv.w += fmaxf(fmaf(hv.w, sc, sf), 0.f);
    ((float4*)out)[i] = xv;
}

// =====================================================================
extern "C" void kernel_launch(void* const* d_in, const int* in_sizes, int n_in,
                              void* d_out, int out_size, void* d_ws, size_t ws_size,
                              hipStream_t stream)
{
    const float* x      = (const float*)d_in[0];
    const float* qkv_w  = (const float*)d_in[1];
    const float* qkv_b  = (const float*)d_in[2];
    const float* proj_w = (const float*)d_in[3];
    const float* proj_b = (const float*)d_in[4];
    const float* w1     = (const float*)d_in[5];
    const float* g1     = (const float*)d_in[6];
    const float* b1     = (const float*)d_in[7];
    const float* w2     = (const float*)d_in[8];
    const float* g2     = (const float*)d_in[9];
    const float* b2     = (const float*)d_in[10];
    float* out = (float*)d_out;

    // Workspace layout (~404 MB):
    //   [0, 384MB): qkv channel-major [B,1536,N]; later reused: h [B,HID,N] in
    //               [0,256MB), h2 [B,C,N] in [256MB,384MB)
    //   then S (1MB), ksum (16KB), BN scale/shift arrays.
    float* qkv_buf = (float*)d_ws;
    float* S      = (float*)((char*)d_ws + (size_t)402653184);
    float* ksum   = S + 262144;
    float* scale1 = ksum + 4096;
    float* shift1 = scale1 + 1024;
    float* scale2 = shift1 + 1024;
    float* shift2 = scale2 + 512;
    float* hbuf  = qkv_buf;                       // [B,HID,N] (256MB)
    float* h2buf = qkv_buf + (size_t)67108864;    // [B,C,N]   (128MB)

    const size_t xbs = (size_t)C_ * N_;

    hipMemsetAsync(S, 0, (262144 + 4096) * sizeof(float), stream);

    // qkv = x^T @ qkv_w + b, phi on q,k channels [0,1024)
    gemm_cn<0, 1, false><<<dim3(64, 12, 8), 256, 0, stream>>>(
        qkv_w, 1536, x, xbs, qkv_buf, (size_t)1536 * N_, C_,
        qkv_b, nullptr, 0, nullptr, nullptr, 1024);

    // S = k_phi v^T, ksum
    attn_kv<<<dim3(8, 64), 256, 0, stream>>>(qkv_buf, S, ksum);

    // attn_out = (q_phi S) / (q_phi ksum + eps), into v-slot
    attn_apply<<<dim3(32, 64), 256, 0, stream>>>(qkv_buf, S, ksum);

    // x1 = x + attn @ proj_w + proj_b  -> d_out
    gemm_cn<0, 2, false><<<dim3(64, 4, 8), 256, 0, stream>>>(
        proj_w, 512, qkv_buf + (size_t)1024 * N_, (size_t)1536 * N_, out, xbs, C_,
        proj_b, x, xbs, nullptr, nullptr, 0);

    // h = w1 @ x1 (raw, BN stats next)
    gemm_cn<1, 0, false><<<dim3(64, 8, 8), 256, 0, stream>>>(
        w1, 512, out, xbs, hbuf, (size_t)HID_ * N_, C_,
        nullptr, nullptr, 0, nullptr, nullptr, 0);

    bn_stats<<<dim3(1024), 256, 0, stream>>>(hbuf, (size_t)HID_ * N_, g1, b1, scale1, shift1);

    // h2 = w2 @ relu(bn1(h))   (BN+ReLU fused into input read)
    gemm_cn<1, 0, true><<<dim3(64, 4, 8), 256, 0, stream>>>(
        w2, 1024, hbuf, (size_t)HID_ * N_, h2buf, xbs, HID_,
        nullptr, nullptr, 0, scale1, shift1, 0);

    bn_stats<<<dim3(512), 256, 0, stream>>>(h2buf, xbs, g2, b2, scale2, shift2);

    // out = x1 + relu(bn2(h2))
    final_add<<<dim3(32768), 256, 0, stream>>>(out, h2buf, scale2, shift2);
}

// Round 2
// 1323.000 us; speedup vs baseline: 2.6658x; 2.6658x over previous
//
#include <hip/hip_runtime.h>
#include <hip/hip_bf16.h>

// Problem constants
#define B_    8
#define C_    512
#define N_    8192
#define H_    8
#define D_    64
#define HID_  1024

constexpr float EPS_ATTN = 1e-6f;
constexpr float EPS_BN   = 1e-5f;

typedef _Float16 half8 __attribute__((ext_vector_type(8)));
typedef _Float16 half4 __attribute__((ext_vector_type(4)));
typedef float    floatx4 __attribute__((ext_vector_type(4)));

// async global->LDS, 16B per lane; LDS dest is wave-uniform base + lane*16
#define GLOAD_LDS(gp, lp) \
  __builtin_amdgcn_global_load_lds((const __attribute__((address_space(1))) void*)(gp), \
                                   (__attribute__((address_space(3))) void*)(lp), 16, 0, 0)

// =====================================================================
// MFMA GEMM, fp16 inputs, f32 accum.
//   D[n][o] = sum_k A[n][k] * W[o][k]      (A: activations n-major, W: [O][K])
// Output written channel-major [o][N_] (f32 float4 or f16 half4 stores).
// Tile 128(n) x 128(o), BK=32, 4 waves in 2x2, each wave 64x64 via 4x4
// fragments of 16x16x32. LDS layout [s=k/8][row][8] -> conflict-optimal
// ds_read_b128 and linear global_load_lds staging.
//   EPI 0: f16 out          (w1 -> h16)
//   EPI 1: f16 out + bias, phi for o<phi_limit   (qkv)
//   EPI 2: f32 out + bias + residual             (proj)
//   EPI 3: f32 out          (w2 -> h2)
// =====================================================================
template<int EPI>
__global__ __launch_bounds__(256)
void gemm_mfma(const _Float16* __restrict__ Abase, size_t a_bstride,
               const _Float16* __restrict__ Wt, int K,
               float* __restrict__ OUTf, size_t outf_bs,
               _Float16* __restrict__ OUTh, size_t outh_bs,
               const float* __restrict__ bias,
               const float* __restrict__ resid, size_t res_bs,
               int phi_limit)
{
    __shared__ _Float16 Al[4096];   // [4][128][8] halfs = 8KB
    __shared__ _Float16 Bl[4096];

    const int tid = threadIdx.x;
    const int b = blockIdx.z;
    const int n_base = blockIdx.x * 128;   // M dim (spatial)
    const int o_base = blockIdx.y * 128;   // N dim (out channels)
    const int w = tid >> 6, l = tid & 63;
    const int wm = w >> 1, wn = w & 1;

    const _Float16* A  = Abase + (size_t)b * a_bstride + (size_t)n_base * K;
    const _Float16* Bw = Wt + (size_t)o_base * K;

    // staging decode: 16B chunk j in [0,512): s=j>>7 (k-subgroup), row=j&127
    // issue0: j=tid, issue1: j=256+tid. Wave-uniform LDS base = j_base*16.
    const int r0 = tid & 127;
    const int s0 = tid >> 7;   // 0..1 (wave-uniform)
    const _Float16* ga0 = A  + (size_t)r0 * K + s0 * 8;
    const _Float16* ga1 = A  + (size_t)r0 * K + (2 + s0) * 8;
    const _Float16* gb0 = Bw + (size_t)r0 * K + s0 * 8;
    const _Float16* gb1 = Bw + (size_t)r0 * K + (2 + s0) * 8;
    _Float16* la0 = &Al[(size_t)(tid & 192) * 8];
    _Float16* la1 = &Al[(size_t)(256 + (tid & 192)) * 8];
    _Float16* lb0 = &Bl[(size_t)(tid & 192) * 8];
    _Float16* lb1 = &Bl[(size_t)(256 + (tid & 192)) * 8];

    floatx4 acc[4][4];
    #pragma unroll
    for (int mi = 0; mi < 4; ++mi)
        #pragma unroll
        for (int ni = 0; ni < 4; ++ni)
            acc[mi][ni] = (floatx4){0.f, 0.f, 0.f, 0.f};

    const int s = l >> 4;       // k-subgroup for fragment reads
    const int r = l & 15;

    for (int c0 = 0; c0 < K; c0 += 32) {
        GLOAD_LDS(ga0 + c0, la0);
        GLOAD_LDS(ga1 + c0, la1);
        GLOAD_LDS(gb0 + c0, lb0);
        GLOAD_LDS(gb1 + c0, lb1);
        __syncthreads();                       // vmcnt(0) drain + barrier
        half8 af[4], bf[4];
        #pragma unroll
        for (int f = 0; f < 4; ++f) {
            af[f] = *(const half8*)&Al[(size_t)(s * 128 + wm * 64 + f * 16 + r) * 8];
            bf[f] = *(const half8*)&Bl[(size_t)(s * 128 + wn * 64 + f * 16 + r) * 8];
        }
        #pragma unroll
        for (int mi = 0; mi < 4; ++mi)
            #pragma unroll
            for (int ni = 0; ni < 4; ++ni)
                acc[mi][ni] = __builtin_amdgcn_mfma_f32_16x16x32_f16(af[mi], bf[ni], acc[mi][ni], 0, 0, 0);
        __syncthreads();
    }

    // epilogue: C/D layout col=l&15 (o), row=(l>>4)*4+reg (n, consecutive)
    #pragma unroll
    for (int mi = 0; mi < 4; ++mi) {
        const int n_g = n_base + wm * 64 + mi * 16 + ((l >> 4) << 2);
        #pragma unroll
        for (int ni = 0; ni < 4; ++ni) {
            const int o_g = o_base + wn * 64 + ni * 16 + (l & 15);
            floatx4 v = acc[mi][ni];
            if (EPI == 1 || EPI == 2) {
                const float bi = bias[o_g];
                v[0] += bi; v[1] += bi; v[2] += bi; v[3] += bi;
            }
            if (EPI == 1) {
                if (o_g < phi_limit) {  // phi(x) = elu(x)+1
                    #pragma unroll
                    for (int j = 0; j < 4; ++j)
                        v[j] = v[j] > 0.f ? v[j] + 1.f : __expf(v[j]);
                }
            }
            if (EPI == 2) {
                const float4 rv = *(const float4*)(resid + (size_t)b * res_bs + (size_t)o_g * N_ + n_g);
                v[0] += rv.x; v[1] += rv.y; v[2] += rv.z; v[3] += rv.w;
            }
            if (EPI == 0 || EPI == 1) {
                half4 hv;
                #pragma unroll
                for (int j = 0; j < 4; ++j) hv[j] = (_Float16)v[j];
                *(half4*)(OUTh + (size_t)b * outh_bs + (size_t)o_g * N_ + n_g) = hv;
            } else {
                *(floatx4*)(OUTf + (size_t)b * outf_bs + (size_t)o_g * N_ + n_g) = v;
            }
        }
    }
}

// =====================================================================
// Tiled transpose + cast: src [R][Cc] (f32 or f16, optional affine+relu
// per input row) -> dst [Cc][R] f16. 64x64 tiles via LDS.
// =====================================================================
template<bool INF16, bool AFFINE>
__global__ __launch_bounds__(256)
void cvtT(const void* __restrict__ src, _Float16* __restrict__ dst,
          int R, int Cc, size_t sbs, size_t dbs,
          const float* __restrict__ scale, const float* __restrict__ shift)
{
    __shared__ _Float16 t[64][72];
    const int tid = threadIdx.x;
    const int b = blockIdx.z;
    const int c0 = blockIdx.x * 64;   // col tile (Cc dim)
    const int r0 = blockIdx.y * 64;   // row tile (R dim)
    const int rl = tid >> 3;          // 0..31
    const int cg = (tid & 7) * 8;
    #pragma unroll
    for (int hh = 0; hh < 2; ++hh) {
        const int rr = rl + hh * 32;
        float vals[8];
        if (INF16) {
            const _Float16* sp = (const _Float16*)src + (size_t)b * sbs + (size_t)(r0 + rr) * Cc + c0 + cg;
            const half8 hv = *(const half8*)sp;
            #pragma unroll
            for (int j = 0; j < 8; ++j) vals[j] = (float)hv[j];
        } else {
            const float* sp = (const float*)src + (size_t)b * sbs + (size_t)(r0 + rr) * Cc + c0 + cg;
            const float4 v0 = *(const float4*)sp;
            const float4 v1 = *(const float4*)(sp + 4);
            vals[0] = v0.x; vals[1] = v0.y; vals[2] = v0.z; vals[3] = v0.w;
            vals[4] = v1.x; vals[5] = v1.y; vals[6] = v1.z; vals[7] = v1.w;
        }
        if (AFFINE) {
            const float sc = scale[r0 + rr], sf = shift[r0 + rr];
            #pragma unroll
            for (int j = 0; j < 8; ++j) vals[j] = fmaxf(fmaf(vals[j], sc, sf), 0.f);
        }
        #pragma unroll
        for (int j = 0; j < 8; ++j) t[rr][cg + j] = (_Float16)vals[j];
    }
    __syncthreads();
    const int cl = tid >> 3;
    const int rg = (tid & 7) * 8;
    #pragma unroll
    for (int hh = 0; hh < 2; ++hh) {
        const int cc = cl + hh * 32;
        half8 o;
        #pragma unroll
        for (int j = 0; j < 8; ++j) o[j] = t[rg + j][cc];
        *(half8*)(dst + (size_t)b * dbs + (size_t)(c0 + cc) * R + r0 + rg) = o;
    }
}

// plain f32 -> f16 cast (weights w1/w2, no transpose)
__global__ __launch_bounds__(256)
void cast_f16(const float* __restrict__ in, _Float16* __restrict__ out, int n4)
{
    const int i = blockIdx.x * 256 + threadIdx.x;
    if (i < n4) {
        const float4 v = *(const float4*)(in + (size_t)i * 4);
        half4 h; h[0] = (_Float16)v.x; h[1] = (_Float16)v.y; h[2] = (_Float16)v.z; h[3] = (_Float16)v.w;
        *(half4*)(out + (size_t)i * 4) = h;
    }
}

// =====================================================================
// Attention stage 1: S[bh,d,e] = sum_n k_phi[d,n]*v[e,n]; ksum[bh,d]
// f16 inputs from qkv buffer, f32 compute, atomics into pre-zeroed ws.
// =====================================================================
__global__ __launch_bounds__(256)
void attn_kv_f16(const _Float16* __restrict__ qkvh, float* __restrict__ S, float* __restrict__ ksum)
{
    constexpr int TNK = 16;
    __shared__ float kt[64][17];
    __shared__ float vt[64][17];
    const int tid = threadIdx.x;
    const int bh = blockIdx.y;
    const int b = bh >> 3, h = bh & 7;
    const size_t kbase = ((size_t)b * 1536 + 512  + h * 64) * N_;
    const size_t vbase = ((size_t)b * 1536 + 1024 + h * 64) * N_;
    const int n0 = blockIdx.x * 1024;

    const int e  = tid & 63;
    const int dg = tid >> 6;
    float s[16];
    #pragma unroll
    for (int i = 0; i < 16; ++i) s[i] = 0.f;
    float ksl = 0.f;

    const int lr = tid >> 2;
    const int lc = (tid & 3) * 4;

    for (int it = 0; it < 1024 / TNK; ++it) {
        const int nt = n0 + it * TNK;
        const half4 k4 = *(const half4*)(qkvh + kbase + (size_t)lr * N_ + nt + lc);
        const half4 v4 = *(const half4*)(qkvh + vbase + (size_t)lr * N_ + nt + lc);
        __syncthreads();
        kt[lr][lc + 0] = (float)k4[0]; kt[lr][lc + 1] = (float)k4[1];
        kt[lr][lc + 2] = (float)k4[2]; kt[lr][lc + 3] = (float)k4[3];
        vt[lr][lc + 0] = (float)v4[0]; vt[lr][lc + 1] = (float)v4[1];
        vt[lr][lc + 2] = (float)v4[2]; vt[lr][lc + 3] = (float)v4[3];
        __syncthreads();
        if (tid < 64) {
            float kk = 0.f;
            #pragma unroll
            for (int nn = 0; nn < TNK; ++nn) kk += kt[tid][nn];
            ksl += kk;
        }
        #pragma unroll
        for (int nn = 0; nn < TNK; ++nn) {
            const float ve = vt[e][nn];
            #pragma unroll
            for (int i = 0; i < 16; ++i)
                s[i] = fmaf(kt[dg * 16 + i][nn], ve, s[i]);
        }
    }
    float* Sb = S + (size_t)bh * 64 * 64;
    #pragma unroll
    for (int i = 0; i < 16; ++i)
        atomicAdd(&Sb[(dg * 16 + i) * 64 + e], s[i]);
    if (tid < 64) atomicAdd(&ksum[bh * 64 + tid], ksl);
}

// =====================================================================
// Attention stage 2: out[n, h*64+e] = (sum_d q[d,n]*S[d,e]) / (q.ks + eps)
// Writes f16, n-major [n][C] -- the proj GEMM's A operand layout.
// =====================================================================
__global__ __launch_bounds__(256)
void attn_apply_f16(const _Float16* __restrict__ qkvh, const float* __restrict__ S,
                    const float* __restrict__ ksum, _Float16* __restrict__ attnb)
{
    const int tid = threadIdx.x;
    const int bh = blockIdx.y;
    const int b = bh >> 3, h = bh & 7;
    const int n = blockIdx.x * 256 + tid;
    const _Float16* __restrict__ qb = qkvh + ((size_t)b * 1536 + h * 64) * N_ + n;
    const float* __restrict__ Sb = S + (size_t)bh * 4096;
    const float* __restrict__ ks = ksum + bh * 64;
    float acc[64];
    #pragma unroll
    for (int e = 0; e < 64; ++e) acc[e] = 0.f;
    float den = EPS_ATTN;
    for (int d = 0; d < 64; ++d) {
        const float qd = (float)qb[(size_t)d * N_];
        den = fmaf(qd, ks[d], den);
        #pragma unroll
        for (int e = 0; e < 64; ++e)
            acc[e] = fmaf(qd, Sb[d * 64 + e], acc[e]);
    }
    const float inv = 1.0f / den;
    _Float16* __restrict__ ob = attnb + ((size_t)b * N_ + n) * C_ + h * 64;
    #pragma unroll
    for (int g = 0; g < 8; ++g) {
        half8 hv;
        #pragma unroll
        for (int j = 0; j < 8; ++j) hv[j] = (_Float16)(acc[g * 8 + j] * inv);
        *(half8*)(ob + g * 8) = hv;
    }
}

// =====================================================================
// BatchNorm stats over (b, n) per channel -> scale/shift form (double acc).
// =====================================================================
template<bool INF16>
__global__ __launch_bounds__(256)
void bn_stats(const void* __restrict__ X, size_t bstride,
              const float* __restrict__ gamma, const float* __restrict__ beta,
              float* __restrict__ scale, float* __restrict__ shift)
{
    const int ch = blockIdx.x;
    const int tid = threadIdx.x;
    double s = 0.0, s2 = 0.0;
    for (int b = 0; b < B_; ++b) {
        if (INF16) {
            const _Float16* base = (const _Float16*)X + (size_t)b * bstride + (size_t)ch * N_;
            for (int i = tid; i < N_ / 8; i += 256) {
                const half8 v = *(const half8*)(base + (size_t)i * 8);
                #pragma unroll
                for (int j = 0; j < 8; ++j) {
                    const float f = (float)v[j];
                    s += (double)f; s2 += (double)f * (double)f;
                }
            }
        } else {
            const float* base = (const float*)X + (size_t)b * bstride + (size_t)ch * N_;
            for (int i = tid; i < N_ / 4; i += 256) {
                const float4 v = *(const float4*)(base + (size_t)i * 4);
                s  += (double)v.x + (double)v.y + (double)v.z + (double)v.w;
                s2 += (double)v.x * v.x + (double)v.y * v.y + (double)v.z * v.z + (double)v.w * v.w;
            }
        }
    }
    __shared__ double sh[256], sh2[256];
    sh[tid] = s; sh2[tid] = s2;
    __syncthreads();
    for (int off = 128; off > 0; off >>= 1) {
        if (tid < off) { sh[tid] += sh[tid + off]; sh2[tid] += sh2[tid + off]; }
        __syncthreads();
    }
    if (tid == 0) {
        const double n = (double)B_ * (double)N_;
        const double mean = sh[0] / n;
        const double var  = sh2[0] / n - mean * mean;
        const double inv  = 1.0 / sqrt(var + (double)EPS_BN);
        const double g = (double)gamma[ch];
        scale[ch] = (float)(g * inv);
        shift[ch] = (float)((double)beta[ch] - mean * g * inv);
    }
}

// =====================================================================
// Final: out += relu(h2*scale2[c] + shift2[c])   (out already holds x1)
// =====================================================================
__global__ __launch_bounds__(256)
void final_add(float* __restrict__ out, const float* __restrict__ h2,
               const float* __restrict__ scale, const float* __restrict__ shift)
{
    const size_t i = (size_t)blockIdx.x * 256 + threadIdx.x;   // float4 index
    const int c = (int)((i >> 11) & (C_ - 1));                 // N/4 = 2048 float4 per row
    const float sc = scale[c], sf = shift[c];
    const float4 hv = ((const float4*)h2)[i];
    float4 xv = ((float4*)out)[i];
    xv.x += fmaxf(fmaf(hv.x, sc, sf), 0.f);
    xv.y += fmaxf(fmaf(hv.y, sc, sf), 0.f);
    xv.z += fmaxf(fmaf(hv.z, sc, sf), 0.f);
    xv.w += fmaxf(fmaf(hv.w, sc, sf), 0.f);
    ((float4*)out)[i] = xv;
}

// =====================================================================
extern "C" void kernel_launch(void* const* d_in, const int* in_sizes, int n_in,
                              void* d_out, int out_size, void* d_ws, size_t ws_size,
                              hipStream_t stream)
{
    const float* x      = (const float*)d_in[0];
    const float* qkv_w  = (const float*)d_in[1];
    const float* qkv_b  = (const float*)d_in[2];
    const float* proj_w = (const float*)d_in[3];
    const float* proj_b = (const float*)d_in[4];
    const float* w1     = (const float*)d_in[5];
    const float* g1     = (const float*)d_in[6];
    const float* b1     = (const float*)d_in[7];
    const float* w2     = (const float*)d_in[8];
    const float* g2     = (const float*)d_in[9];
    const float* b2     = (const float*)d_in[10];
    float* out = (float*)d_out;

    // Workspace layout (~391 MB, sequential reuse):
    //  [0,192M):   qkvh f16 [8][1536][8192]; later h16 f16 [8][1024][8192]
    //              (128M), then h2 f32 [8][512][8192] (128M) over h16.
    //  [192,320M): ht f16 [8][8192][1024]
    //  [320,384M): xb -> attnb -> x1b  f16 [8][8192][512] (sequential reuse)
    //  [384M..):   f16 weights, S, ksum, BN scale/shift
    const size_t MB = 1ull << 20;
    char* ws = (char*)d_ws;
    _Float16* qkvh   = (_Float16*)ws;
    _Float16* h16    = (_Float16*)ws;
    float*    h2     = (float*)ws;
    _Float16* ht     = (_Float16*)(ws + 192 * MB);
    _Float16* xb     = (_Float16*)(ws + 320 * MB);
    _Float16* attnb  = xb;
    _Float16* x1b    = xb;
    _Float16* qkvwT  = (_Float16*)(ws + 384 * MB);
    _Float16* projwT = qkvwT + 1536 * 512;
    _Float16* w1h    = projwT + 512 * 512;
    _Float16* w2h    = w1h + 1024 * 512;
    float* S      = (float*)(ws + 390 * MB);
    float* ksum   = S + 262144;
    float* scale1 = ksum + 4096;
    float* shift1 = scale1 + 1024;
    float* scale2 = shift1 + 1024;
    float* shift2 = scale2 + 512;

    const size_t xbs = (size_t)C_ * N_;

    // ---- weight conversion (tiny) ----
    cvtT<false, false><<<dim3(24, 8, 1), 256, 0, stream>>>(qkv_w, qkvwT, 512, 1536, 0, 0, nullptr, nullptr);
    cvtT<false, false><<<dim3(8, 8, 1), 256, 0, stream>>>(proj_w, projwT, 512, 512, 0, 0, nullptr, nullptr);
    cast_f16<<<512, 256, 0, stream>>>(w1, w1h, 131072);
    cast_f16<<<512, 256, 0, stream>>>(w2, w2h, 131072);

    // ---- x -> xb (n-major f16) ----
    cvtT<false, false><<<dim3(128, 8, 8), 256, 0, stream>>>(x, xb, 512, 8192, xbs, (size_t)N_ * C_, nullptr, nullptr);

    hipMemsetAsync(S, 0, (262144 + 4096) * sizeof(float), stream);

    // ---- qkv GEMM: f16 out + bias + phi(q,k) ----
    gemm_mfma<1><<<dim3(64, 12, 8), 256, 0, stream>>>(
        xb, (size_t)N_ * 512, qkvwT, 512,
        nullptr, 0, qkvh, (size_t)1536 * N_, qkv_b, nullptr, 0, 1024);

    // ---- attention core (f32 compute, f16 I/O) ----
    attn_kv_f16<<<dim3(8, 64), 256, 0, stream>>>(qkvh, S, ksum);
    attn_apply_f16<<<dim3(32, 64), 256, 0, stream>>>(qkvh, S, ksum, attnb);

    // ---- proj GEMM: f32 out + bias + residual -> d_out ----
    gemm_mfma<2><<<dim3(64, 4, 8), 256, 0, stream>>>(
        attnb, (size_t)N_ * 512, projwT, 512,
        out, xbs, nullptr, 0, proj_b, x, xbs, 0);

    // ---- x1 -> x1b (n-major f16) ----
    cvtT<false, false><<<dim3(128, 8, 8), 256, 0, stream>>>(out, x1b, 512, 8192, xbs, (size_t)N_ * C_, nullptr, nullptr);

    // ---- w1 GEMM: h16 (f16, channel-major) ----
    gemm_mfma<0><<<dim3(64, 8, 8), 256, 0, stream>>>(
        x1b, (size_t)N_ * 512, w1h, 512,
        nullptr, 0, h16, (size_t)HID_ * N_, nullptr, nullptr, 0, 0);

    bn_stats<true><<<1024, 256, 0, stream>>>(h16, (size_t)HID_ * N_, g1, b1, scale1, shift1);

    // ---- bn1+relu fused into transpose: h16 -> ht (n-major f16) ----
    cvtT<true, true><<<dim3(128, 16, 8), 256, 0, stream>>>(
        h16, ht, 1024, 8192, (size_t)HID_ * N_, (size_t)N_ * HID_, scale1, shift1);

    // ---- w2 GEMM: h2 (f32, channel-major) ----
    gemm_mfma<3><<<dim3(64, 4, 8), 256, 0, stream>>>(
        ht, (size_t)N_ * 1024, w2h, 1024,
        h2, xbs, nullptr, 0, nullptr, nullptr, 0, 0);

    bn_stats<false><<<512, 256, 0, stream>>>(h2, xbs, g2, b2, scale2, shift2);

    // ---- out = x1 + relu(bn2(h2)) ----
    final_add<<<32768, 256, 0, stream>>>(out, h2, scale2, shift2);
}

// Round 3
// 1172.563 us; speedup vs baseline: 3.0078x; 1.1283x over previous
//
#include <hip/hip_runtime.h>
#include <hip/hip_bf16.h>

// Problem constants
#define B_    8
#define C_    512
#define N_    8192
#define H_    8
#define D_    64
#define HID_  1024

constexpr float EPS_ATTN = 1e-6f;
constexpr float EPS_BN   = 1e-5f;

typedef _Float16 half8 __attribute__((ext_vector_type(8)));
typedef _Float16 half4 __attribute__((ext_vector_type(4)));
typedef float    floatx4 __attribute__((ext_vector_type(4)));

// async global->LDS, 16B per lane; LDS dest is wave-uniform base + lane*16
#define GLOAD_LDS(gp, lp) \
  __builtin_amdgcn_global_load_lds((const __attribute__((address_space(1))) void*)(gp), \
                                   (__attribute__((address_space(3))) void*)(lp), 16, 0, 0)

// =====================================================================
// MFMA GEMM, fp16 inputs, f32 accum, 2-phase double-buffered pipeline.
//   D[n][o] = sum_k A[n][k] * W[o][k]      (A: activations n-major, W: [O][K])
// Output written channel-major [o][N_].
// Tile 128(n) x 128(o), BK=32, 4 waves 2x2, per-wave 64x64 via 4x4 frags
// of 16x16x32. LDS [s=k/8][row][8] halfs: linear for global_load_lds,
// conflict-free ds_read_b128 (verified: SQ_LDS_BANK_CONFLICT=0).
//   EPI 0: f16 out                              (w1 -> h16, w2 -> h2h)
//   EPI 1: f16 out + bias, phi for o<phi_limit  (qkv)
//   EPI 2: f32 out + bias + residual            (proj)
// =====================================================================
template<int EPI>
__global__ __launch_bounds__(256)
void gemm_mfma(const _Float16* __restrict__ Abase, size_t a_bstride,
               const _Float16* __restrict__ Wt, int K,
               float* __restrict__ OUTf, size_t outf_bs,
               _Float16* __restrict__ OUTh, size_t outh_bs,
               const float* __restrict__ bias,
               const float* __restrict__ resid, size_t res_bs,
               int phi_limit)
{
    __shared__ _Float16 Al0[4096], Al1[4096];   // 8KB each
    __shared__ _Float16 Bl0[4096], Bl1[4096];

    const int tid = threadIdx.x;
    const int b = blockIdx.z;
    const int n_base = blockIdx.x * 128;   // M dim (spatial)
    const int o_base = blockIdx.y * 128;   // N dim (out channels)
    const int w = tid >> 6, l = tid & 63;
    const int wm = w >> 1, wn = w & 1;

    const _Float16* A  = Abase + (size_t)b * a_bstride + (size_t)n_base * K;
    const _Float16* Bw = Wt + (size_t)o_base * K;

    // staging decode: 16B chunk j in [0,512): s=j>>7 (k-subgroup), row=j&127
    const int r0 = tid & 127;
    const int s0 = tid >> 7;   // wave-pair-uniform
    const _Float16* ga0 = A  + (size_t)r0 * K + s0 * 8;
    const _Float16* ga1 = A  + (size_t)r0 * K + (2 + s0) * 8;
    const _Float16* gb0 = Bw + (size_t)r0 * K + s0 * 8;
    const _Float16* gb1 = Bw + (size_t)r0 * K + (2 + s0) * 8;
    const int loff = (tid & 192) * 8;   // wave-uniform LDS base (halfs)

    floatx4 acc[4][4];
    #pragma unroll
    for (int mi = 0; mi < 4; ++mi)
        #pragma unroll
        for (int ni = 0; ni < 4; ++ni)
            acc[mi][ni] = (floatx4){0.f, 0.f, 0.f, 0.f};

    const int s = l >> 4;       // k-subgroup for fragment reads
    const int r = l & 15;

    auto stage = [&](_Float16* AlB, _Float16* BlB, int c0) {
        GLOAD_LDS(ga0 + c0, AlB + loff);
        GLOAD_LDS(ga1 + c0, AlB + 2048 + loff);
        GLOAD_LDS(gb0 + c0, BlB + loff);
        GLOAD_LDS(gb1 + c0, BlB + 2048 + loff);
    };
    auto compute = [&](const _Float16* AlB, const _Float16* BlB) {
        half8 af[4], bf[4];
        #pragma unroll
        for (int f = 0; f < 4; ++f) {
            af[f] = *(const half8*)&AlB[(size_t)(s * 128 + wm * 64 + f * 16 + r) * 8];
            bf[f] = *(const half8*)&BlB[(size_t)(s * 128 + wn * 64 + f * 16 + r) * 8];
        }
        #pragma unroll
        for (int mi = 0; mi < 4; ++mi)
            #pragma unroll
            for (int ni = 0; ni < 4; ++ni)
                acc[mi][ni] = __builtin_amdgcn_mfma_f32_16x16x32_f16(af[mi], bf[ni], acc[mi][ni], 0, 0, 0);
    };

    // 2-phase pipeline: STAGE(next) issued before compute(cur); the single
    // __syncthreads (vmcnt0+lgkmcnt0+barrier) per half-iter drains it while
    // compute hides most of the load latency. NT is even (K=512/1024).
    const int NT = K >> 5;
    stage(Al0, Bl0, 0);
    __syncthreads();
    for (int t = 0; t < NT; t += 2) {
        stage(Al1, Bl1, (t + 1) << 5);
        compute(Al0, Bl0);
        __syncthreads();
        if (t + 2 < NT) stage(Al0, Bl0, (t + 2) << 5);
        compute(Al1, Bl1);
        __syncthreads();
    }

    // epilogue: C/D layout col=l&15 (o), row=(l>>4)*4+reg (n, consecutive)
    #pragma unroll
    for (int mi = 0; mi < 4; ++mi) {
        const int n_g = n_base + wm * 64 + mi * 16 + ((l >> 4) << 2);
        #pragma unroll
        for (int ni = 0; ni < 4; ++ni) {
            const int o_g = o_base + wn * 64 + ni * 16 + (l & 15);
            floatx4 v = acc[mi][ni];
            if (EPI == 1 || EPI == 2) {
                const float bi = bias[o_g];
                v[0] += bi; v[1] += bi; v[2] += bi; v[3] += bi;
            }
            if (EPI == 1) {
                if (o_g < phi_limit) {  // phi(x) = elu(x)+1
                    #pragma unroll
                    for (int j = 0; j < 4; ++j)
                        v[j] = v[j] > 0.f ? v[j] + 1.f : __expf(v[j]);
                }
            }
            if (EPI == 2) {
                const float4 rv = *(const float4*)(resid + (size_t)b * res_bs + (size_t)o_g * N_ + n_g);
                v[0] += rv.x; v[1] += rv.y; v[2] += rv.z; v[3] += rv.w;
                *(floatx4*)(OUTf + (size_t)b * outf_bs + (size_t)o_g * N_ + n_g) = v;
            } else {
                half4 hv;
                #pragma unroll
                for (int j = 0; j < 4; ++j) hv[j] = (_Float16)v[j];
                *(half4*)(OUTh + (size_t)b * outh_bs + (size_t)o_g * N_ + n_g) = hv;
            }
        }
    }
}

// =====================================================================
// Tiled transpose + cast: src [R][Cc] (f32 or f16, optional affine+relu
// per input row) -> dst [Cc][R] f16. 64x64 tiles via LDS.
// Pad 76 halfs (word-stride 38): 8-row read stride = 304 words == 16 mod 32
// -> <=4-way conflict (72 gave 8-way); rows stay 8B-aligned for half4.
// =====================================================================
template<bool INF16, bool AFFINE>
__global__ __launch_bounds__(256)
void cvtT(const void* __restrict__ src, _Float16* __restrict__ dst,
          int R, int Cc, size_t sbs, size_t dbs,
          const float* __restrict__ scale, const float* __restrict__ shift)
{
    __shared__ _Float16 t[64][76];
    const int tid = threadIdx.x;
    const int b = blockIdx.z;
    const int c0 = blockIdx.x * 64;   // col tile (Cc dim)
    const int r0 = blockIdx.y * 64;   // row tile (R dim)
    const int rl = tid >> 3;          // 0..31
    const int cg = (tid & 7) * 8;
    #pragma unroll
    for (int hh = 0; hh < 2; ++hh) {
        const int rr = rl + hh * 32;
        float vals[8];
        if (INF16) {
            const _Float16* sp = (const _Float16*)src + (size_t)b * sbs + (size_t)(r0 + rr) * Cc + c0 + cg;
            const half8 hv = *(const half8*)sp;
            #pragma unroll
            for (int j = 0; j < 8; ++j) vals[j] = (float)hv[j];
        } else {
            const float* sp = (const float*)src + (size_t)b * sbs + (size_t)(r0 + rr) * Cc + c0 + cg;
            const float4 v0 = *(const float4*)sp;
            const float4 v1 = *(const float4*)(sp + 4);
            vals[0] = v0.x; vals[1] = v0.y; vals[2] = v0.z; vals[3] = v0.w;
            vals[4] = v1.x; vals[5] = v1.y; vals[6] = v1.z; vals[7] = v1.w;
        }
        if (AFFINE) {
            const float sc = scale[r0 + rr], sf = shift[r0 + rr];
            #pragma unroll
            for (int j = 0; j < 8; ++j) vals[j] = fmaxf(fmaf(vals[j], sc, sf), 0.f);
        }
        #pragma unroll
        for (int j = 0; j < 8; ++j) t[rr][cg + j] = (_Float16)vals[j];
    }
    __syncthreads();
    const int cl = tid >> 3;
    const int rg = (tid & 7) * 8;
    #pragma unroll
    for (int hh = 0; hh < 2; ++hh) {
        const int cc = cl + hh * 32;
        half8 o;
        #pragma unroll
        for (int j = 0; j < 8; ++j) o[j] = t[rg + j][cc];
        *(half8*)(dst + (size_t)b * dbs + (size_t)(c0 + cc) * R + r0 + rg) = o;
    }
}

// plain f32 -> f16 cast (weights w1/w2, no transpose)
__global__ __launch_bounds__(256)
void cast_f16(const float* __restrict__ in, _Float16* __restrict__ out, int n4)
{
    const int i = blockIdx.x * 256 + threadIdx.x;
    if (i < n4) {
        const float4 v = *(const float4*)(in + (size_t)i * 4);
        half4 h; h[0] = (_Float16)v.x; h[1] = (_Float16)v.y; h[2] = (_Float16)v.z; h[3] = (_Float16)v.w;
        *(half4*)(out + (size_t)i * 4) = h;
    }
}

// =====================================================================
// Attention stage 1 via MFMA: per (bh, n-chunk of 1024):
//   S_part[d][e] = sum_n k_phi[d][n] * v[e][n]   (both K-contiguous rows)
//   ks_part[d]   = sum_n k_phi[d][n]  (ones-operand MFMA)
// Wave w owns d-range w*16..+15 (af), 4 e-fragments (bf). 2-phase staged.
// Plain partial stores (no atomics, no zero-init).
// =====================================================================
__global__ __launch_bounds__(256)
void attn_kv_mfma(const _Float16* __restrict__ qkvh,
                  float* __restrict__ S_part, float* __restrict__ ks_part)
{
    __shared__ _Float16 kt0[2048], kt1[2048], vt0[2048], vt1[2048];  // 4KB each
    const int tid = threadIdx.x;
    const int bh = blockIdx.y;
    const int b = bh >> 3, h = bh & 7;
    const size_t kbase = ((size_t)b * 1536 + 512  + h * 64) * N_;
    const size_t vbase = ((size_t)b * 1536 + 1024 + h * 64) * N_;
    const int n0 = blockIdx.x * 1024;
    const int w = tid >> 6, l = tid & 63;

    // staging: chunk j=tid in [0,256): s=j>>6 (k-sub), row=j&63 (d/e)
    const int rr = tid & 63, ss = tid >> 6;
    const _Float16* gk = qkvh + kbase + (size_t)rr * N_ + n0 + ss * 8;
    const _Float16* gv = qkvh + vbase + (size_t)rr * N_ + n0 + ss * 8;
    const int loff = (tid & 192) * 8;

    floatx4 acc[4], accks;
    #pragma unroll
    for (int ni = 0; ni < 4; ++ni) acc[ni] = (floatx4){0.f, 0.f, 0.f, 0.f};
    accks = (floatx4){0.f, 0.f, 0.f, 0.f};

    const int s = l >> 4, r = l & 15;
    const int drow = w * 16 + r;
    half8 onesv;
    #pragma unroll
    for (int j = 0; j < 8; ++j) onesv[j] = (_Float16)1.0f;

    auto stage = [&](_Float16* kB, _Float16* vB, int nt) {
        GLOAD_LDS(gk + nt, kB + loff);
        GLOAD_LDS(gv + nt, vB + loff);
    };
    auto compute = [&](const _Float16* kB, const _Float16* vB) {
        const half8 af = *(const half8*)&kB[(size_t)(s * 64 + drow) * 8];
        half8 bf[4];
        #pragma unroll
        for (int ni = 0; ni < 4; ++ni)
            bf[ni] = *(const half8*)&vB[(size_t)(s * 64 + ni * 16 + r) * 8];
        #pragma unroll
        for (int ni = 0; ni < 4; ++ni)
            acc[ni] = __builtin_amdgcn_mfma_f32_16x16x32_f16(af, bf[ni], acc[ni], 0, 0, 0);
        accks = __builtin_amdgcn_mfma_f32_16x16x32_f16(af, onesv, accks, 0, 0, 0);
    };

    stage(kt0, vt0, 0);
    __syncthreads();
    for (int t = 0; t < 32; t += 2) {
        stage(kt1, vt1, (t + 1) * 32);
        compute(kt0, vt0);
        __syncthreads();
        if (t + 2 < 32) stage(kt0, vt0, (t + 2) * 32);
        compute(kt1, vt1);
        __syncthreads();
    }

    float* Sp = S_part + ((size_t)blockIdx.x * 64 + bh) * 4096;
    #pragma unroll
    for (int ni = 0; ni < 4; ++ni)
        #pragma unroll
        for (int j = 0; j < 4; ++j)
            Sp[(w * 16 + s * 4 + j) * 64 + ni * 16 + r] = acc[ni][j];
    if (r == 0) {
        float* kp = ks_part + ((size_t)blockIdx.x * 64 + bh) * 64;
        #pragma unroll
        for (int j = 0; j < 4; ++j) kp[w * 16 + s * 4 + j] = accks[j];
    }
}

// Sum the 8 n-chunk partials -> S[bh][4096], ksum[bh][64]
__global__ __launch_bounds__(256)
void attn_reduce(const float* __restrict__ S_part, const float* __restrict__ ks_part,
                 float* __restrict__ S, float* __restrict__ ksum)
{
    const int bh = blockIdx.x;
    const int tid = threadIdx.x;
    for (int i = tid; i < 4096; i += 256) {
        float s = 0.f;
        #pragma unroll
        for (int c = 0; c < 8; ++c) s += S_part[((size_t)c * 64 + bh) * 4096 + i];
        S[(size_t)bh * 4096 + i] = s;
    }
    if (tid < 64) {
        float s = 0.f;
        #pragma unroll
        for (int c = 0; c < 8; ++c) s += ks_part[((size_t)c * 64 + bh) * 64 + tid];
        ksum[bh * 64 + tid] = s;
    }
}

// =====================================================================
// Attention stage 2: out[n, h*64+e] = (sum_d q[d,n]*S[d,e]) / (q.ks + eps)
// Writes f16, n-major [n][C] -- the proj GEMM's A operand layout.
// =====================================================================
__global__ __launch_bounds__(256)
void attn_apply_f16(const _Float16* __restrict__ qkvh, const float* __restrict__ S,
                    const float* __restrict__ ksum, _Float16* __restrict__ attnb)
{
    const int tid = threadIdx.x;
    const int bh = blockIdx.y;
    const int b = bh >> 3, h = bh & 7;
    const int n = blockIdx.x * 256 + tid;
    const _Float16* __restrict__ qb = qkvh + ((size_t)b * 1536 + h * 64) * N_ + n;
    const float* __restrict__ Sb = S + (size_t)bh * 4096;
    const float* __restrict__ ks = ksum + bh * 64;
    float acc[64];
    #pragma unroll
    for (int e = 0; e < 64; ++e) acc[e] = 0.f;
    float den = EPS_ATTN;
    for (int d = 0; d < 64; ++d) {
        const float qd = (float)qb[(size_t)d * N_];
        den = fmaf(qd, ks[d], den);
        #pragma unroll
        for (int e = 0; e < 64; ++e)
            acc[e] = fmaf(qd, Sb[d * 64 + e], acc[e]);
    }
    const float inv = 1.0f / den;
    _Float16* __restrict__ ob = attnb + ((size_t)b * N_ + n) * C_ + h * 64;
    #pragma unroll
    for (int g = 0; g < 8; ++g) {
        half8 hv;
        #pragma unroll
        for (int j = 0; j < 8; ++j) hv[j] = (_Float16)(acc[g * 8 + j] * inv);
        *(half8*)(ob + g * 8) = hv;
    }
}

// =====================================================================
// BatchNorm stats over (b, n) per channel -> scale/shift form (double acc).
// =====================================================================
__global__ __launch_bounds__(256)
void bn_stats_h(const _Float16* __restrict__ X, size_t bstride,
                const float* __restrict__ gamma, const float* __restrict__ beta,
                float* __restrict__ scale, float* __restrict__ shift)
{
    const int ch = blockIdx.x;
    const int tid = threadIdx.x;
    double s = 0.0, s2 = 0.0;
    for (int b = 0; b < B_; ++b) {
        const _Float16* base = X + (size_t)b * bstride + (size_t)ch * N_;
        for (int i = tid; i < N_ / 8; i += 256) {
            const half8 v = *(const half8*)(base + (size_t)i * 8);
            #pragma unroll
            for (int j = 0; j < 8; ++j) {
                const float f = (float)v[j];
                s += (double)f; s2 += (double)f * (double)f;
            }
        }
    }
    __shared__ double sh[256], sh2[256];
    sh[tid] = s; sh2[tid] = s2;
    __syncthreads();
    for (int off = 128; off > 0; off >>= 1) {
        if (tid < off) { sh[tid] += sh[tid + off]; sh2[tid] += sh2[tid + off]; }
        __syncthreads();
    }
    if (tid == 0) {
        const double n = (double)B_ * (double)N_;
        const double mean = sh[0] / n;
        const double var  = sh2[0] / n - mean * mean;
        const double inv  = 1.0 / sqrt(var + (double)EPS_BN);
        const double g = (double)gamma[ch];
        scale[ch] = (float)(g * inv);
        shift[ch] = (float)((double)beta[ch] - mean * g * inv);
    }
}

// =====================================================================
// Final: out = x1 + relu(h2*scale2[c] + shift2[c]), h2 in f16
// =====================================================================
__global__ __launch_bounds__(256)
void final_add_h(float* __restrict__ out, const _Float16* __restrict__ h2,
                 const float* __restrict__ scale, const float* __restrict__ shift)
{
    const size_t i = (size_t)blockIdx.x * 256 + threadIdx.x;   // half8-chunk idx
    const int c = (int)((i >> 10) & (C_ - 1));                 // N/8 = 1024 chunks/row
    const float sc = scale[c], sf = shift[c];
    const half8 hv = *(const half8*)(h2 + i * 8);
    float4 x0 = ((float4*)out)[i * 2];
    float4 x1 = ((float4*)out)[i * 2 + 1];
    x0.x += fmaxf(fmaf((float)hv[0], sc, sf), 0.f);
    x0.y += fmaxf(fmaf((float)hv[1], sc, sf), 0.f);
    x0.z += fmaxf(fmaf((float)hv[2], sc, sf), 0.f);
    x0.w += fmaxf(fmaf((float)hv[3], sc, sf), 0.f);
    x1.x += fmaxf(fmaf((float)hv[4], sc, sf), 0.f);
    x1.y += fmaxf(fmaf((float)hv[5], sc, sf), 0.f);
    x1.z += fmaxf(fmaf((float)hv[6], sc, sf), 0.f);
    x1.w += fmaxf(fmaf((float)hv[7], sc, sf), 0.f);
    ((float4*)out)[i * 2] = x0;
    ((float4*)out)[i * 2 + 1] = x1;
}

// =====================================================================
extern "C" void kernel_launch(void* const* d_in, const int* in_sizes, int n_in,
                              void* d_out, int out_size, void* d_ws, size_t ws_size,
                              hipStream_t stream)
{
    const float* x      = (const float*)d_in[0];
    const float* qkv_w  = (const float*)d_in[1];
    const float* qkv_b  = (const float*)d_in[2];
    const float* proj_w = (const float*)d_in[3];
    const float* proj_b = (const float*)d_in[4];
    const float* w1     = (const float*)d_in[5];
    const float* g1     = (const float*)d_in[6];
    const float* b1     = (const float*)d_in[7];
    const float* w2     = (const float*)d_in[8];
    const float* g2     = (const float*)d_in[9];
    const float* b2     = (const float*)d_in[10];
    float* out = (float*)d_out;

    // Workspace layout (~388 MB, sequential reuse):
    //  [0,192M):   qkvh f16 [8][1536][8192]; later h16 f16 [8][1024][8192]
    //              in [0,128M) and h2h f16 [8][512][8192] in [128,192M)
    //  [192,320M): attn scratch (S_part 8M, ks_part, S, ksum) early; then
    //              ht f16 [8][8192][1024] (written after attn is dead)
    //  [320,384M): xb -> attnb -> x1b  f16 [8][8192][512] (sequential reuse)
    //  [384M..):   f16 weights, BN scale/shift
    const size_t MB = 1ull << 20;
    char* ws = (char*)d_ws;
    _Float16* qkvh   = (_Float16*)ws;
    _Float16* h16    = (_Float16*)ws;
    _Float16* h2h    = (_Float16*)(ws + 128 * MB);
    float*    S_part = (float*)(ws + 192 * MB);     // 8MB
    float*    ks_part= (float*)(ws + 200 * MB);     // 128KB
    float*    S      = (float*)(ws + 201 * MB);     // 1MB
    float*    ksum   = (float*)(ws + 202 * MB);     // 16KB
    _Float16* ht     = (_Float16*)(ws + 192 * MB);
    _Float16* xb     = (_Float16*)(ws + 320 * MB);
    _Float16* attnb  = xb;
    _Float16* x1b    = xb;
    _Float16* qkvwT  = (_Float16*)(ws + 384 * MB);
    _Float16* projwT = qkvwT + 1536 * 512;
    _Float16* w1h    = projwT + 512 * 512;
    _Float16* w2h    = w1h + 1024 * 512;
    float* scale1 = (float*)(w2h + 512 * 1024);
    float* shift1 = scale1 + 1024;
    float* scale2 = shift1 + 1024;
    float* shift2 = scale2 + 512;

    const size_t xbs = (size_t)C_ * N_;

    // ---- weight conversion (tiny) ----
    cvtT<false, false><<<dim3(24, 8, 1), 256, 0, stream>>>(qkv_w, qkvwT, 512, 1536, 0, 0, nullptr, nullptr);
    cvtT<false, false><<<dim3(8, 8, 1), 256, 0, stream>>>(proj_w, projwT, 512, 512, 0, 0, nullptr, nullptr);
    cast_f16<<<512, 256, 0, stream>>>(w1, w1h, 131072);
    cast_f16<<<512, 256, 0, stream>>>(w2, w2h, 131072);

    // ---- x -> xb (n-major f16) ----
    cvtT<false, false><<<dim3(128, 8, 8), 256, 0, stream>>>(x, xb, 512, 8192, xbs, (size_t)N_ * C_, nullptr, nullptr);

    // ---- qkv GEMM: f16 out + bias + phi(q,k) ----
    gemm_mfma<1><<<dim3(64, 12, 8), 256, 0, stream>>>(
        xb, (size_t)N_ * 512, qkvwT, 512,
        nullptr, 0, qkvh, (size_t)1536 * N_, qkv_b, nullptr, 0, 1024);

    // ---- attention core ----
    attn_kv_mfma<<<dim3(8, 64), 256, 0, stream>>>(qkvh, S_part, ks_part);
    attn_reduce<<<64, 256, 0, stream>>>(S_part, ks_part, S, ksum);
    attn_apply_f16<<<dim3(32, 64), 256, 0, stream>>>(qkvh, S, ksum, attnb);

    // ---- proj GEMM: f32 out + bias + residual -> d_out ----
    gemm_mfma<2><<<dim3(64, 4, 8), 256, 0, stream>>>(
        attnb, (size_t)N_ * 512, projwT, 512,
        out, xbs, nullptr, 0, proj_b, x, xbs, 0);

    // ---- x1 -> x1b (n-major f16) ----
    cvtT<false, false><<<dim3(128, 8, 8), 256, 0, stream>>>(out, x1b, 512, 8192, xbs, (size_t)N_ * C_, nullptr, nullptr);

    // ---- w1 GEMM: h16 (f16, channel-major) ----
    gemm_mfma<0><<<dim3(64, 8, 8), 256, 0, stream>>>(
        x1b, (size_t)N_ * 512, w1h, 512,
        nullptr, 0, h16, (size_t)HID_ * N_, nullptr, nullptr, 0, 0);

    bn_stats_h<<<1024, 256, 0, stream>>>(h16, (size_t)HID_ * N_, g1, b1, scale1, shift1);

    // ---- bn1+relu fused into transpose: h16 -> ht (n-major f16) ----
    cvtT<true, true><<<dim3(128, 16, 8), 256, 0, stream>>>(
        h16, ht, 1024, 8192, (size_t)HID_ * N_, (size_t)N_ * HID_, scale1, shift1);

    // ---- w2 GEMM: h2h (f16, channel-major) ----
    gemm_mfma<0><<<dim3(64, 4, 8), 256, 0, stream>>>(
        ht, (size_t)N_ * 1024, w2h, 1024,
        nullptr, 0, h2h, xbs, nullptr, nullptr, 0, 0);

    bn_stats_h<<<512, 256, 0, stream>>>(h2h, xbs, g2, b2, scale2, shift2);

    // ---- out = x1 + relu(bn2(h2)) ----
    final_add_h<<<16384, 256, 0, stream>>>(out, h2h, scale2, shift2);
}